// Round 2
// baseline (199.194 us; speedup 1.0000x reference)
//
#include <hip/hip_runtime.h>
#include <hip/hip_bf16.h>

#define NROWS 8192
#define DDIM  256
#define INV_TEMP 20.0f   // 1/0.05

typedef __attribute__((ext_vector_type(8))) short bf16x8;
typedef __attribute__((ext_vector_type(4))) float f32x4;

// ---------------------------------------------------------------------------
// Kernel 1: per-row L2-normalize q and p (fp32), emit bf16 copies, fp32 diag.
// One wave per row, 4 rows (4 waves) per block.
// ---------------------------------------------------------------------------
__global__ __launch_bounds__(256) void norm_diag_kernel(
    const float* __restrict__ q, const float* __restrict__ p,
    unsigned short* __restrict__ qn, unsigned short* __restrict__ pn,
    float* __restrict__ diag)
{
    const int row  = (blockIdx.x << 2) + (threadIdx.x >> 6);
    const int lane = threadIdx.x & 63;

    const float4 qv = ((const float4*)(q + (size_t)row * DDIM))[lane];
    const float4 pv = ((const float4*)(p + (size_t)row * DDIM))[lane];

    float sq = qv.x*qv.x + qv.y*qv.y + qv.z*qv.z + qv.w*qv.w;
    float sp = pv.x*pv.x + pv.y*pv.y + pv.z*pv.z + pv.w*pv.w;
    #pragma unroll
    for (int m = 1; m < 64; m <<= 1) {
        sq += __shfl_xor(sq, m);
        sp += __shfl_xor(sp, m);
    }
    const float qs = 1.0f / fmaxf(sqrtf(sq), 1e-8f);
    const float ps = 1.0f / fmaxf(sqrtf(sp), 1e-8f);

    const float qx = qv.x*qs, qy = qv.y*qs, qz = qv.z*qs, qw = qv.w*qs;
    const float px = pv.x*ps, py = pv.y*ps, pz = pv.z*ps, pw = pv.w*ps;

    float d = qx*px + qy*py + qz*pz + qw*pw;
    #pragma unroll
    for (int m = 1; m < 64; m <<= 1) d += __shfl_xor(d, m);
    if (lane == 0) diag[row] = d * INV_TEMP;

    union { unsigned short u16[4]; uint2 v; } uq, up;
    {
        __hip_bfloat16 b;
        b = __float2bfloat16(qx); uq.u16[0] = *(unsigned short*)&b;
        b = __float2bfloat16(qy); uq.u16[1] = *(unsigned short*)&b;
        b = __float2bfloat16(qz); uq.u16[2] = *(unsigned short*)&b;
        b = __float2bfloat16(qw); uq.u16[3] = *(unsigned short*)&b;
        b = __float2bfloat16(px); up.u16[0] = *(unsigned short*)&b;
        b = __float2bfloat16(py); up.u16[1] = *(unsigned short*)&b;
        b = __float2bfloat16(pz); up.u16[2] = *(unsigned short*)&b;
        b = __float2bfloat16(pw); up.u16[3] = *(unsigned short*)&b;
    }
    *(uint2*)(qn + (size_t)row * DDIM + lane * 4) = uq.v;
    *(uint2*)(pn + (size_t)row * DDIM + lane * 4) = up.v;
}

// ---------------------------------------------------------------------------
// Kernel 2: fused GEMM + sum-exp, NO LDS STAGING.
// Key fact: the mfma_f32_16x16x32_bf16 A/B fragment (lane l16 -> 16 contiguous
// bytes of row l16 at k-offset quad*8) IS the row-major global layout of
// qn/pn. The previous LDS tile was a pass-through; its only function was
// 2-way sharing between wave pairs, while qn+pn (8 MB) is fully L2/L3
// resident (per-XCD hot set ~1.3 MB). So: load fragments straight from
// global into registers, explicit 2-deep register double-buffer, ZERO
// barriers in the K-loop. Waves free-run; 12 waves/CU hide L2 latency.
// Block = 256 threads (4 waves, 2x2 wave grid), tile = 128x128, BK=32 x 8.
// LDS: 1 KB (epilogue reduction only).
// ---------------------------------------------------------------------------
__global__ __launch_bounds__(256, 3) void simexp_kernel(
    const unsigned short* __restrict__ qn,
    const unsigned short* __restrict__ pn,
    float* __restrict__ part)       // [64 colblocks][8192 rows]
{
    __shared__ float red[256];      // epilogue only

    const int tid  = threadIdx.x;
    const int lane = tid & 63;
    const int w    = tid >> 6;        // wave 0..3
    const int wr   = w >> 1;          // wave row (0..1)
    const int wc   = w & 1;           // wave col (0..1)
    const int quad = lane >> 4;
    const int l16  = lane & 15;
    const int rowbase = blockIdx.y * 128;
    const int colbase = blockIdx.x * 128;

    // fragment base pointers: wave (wr,wc) owns rows [wr*64,+64), cols [wc*64,+64)
    // af[i]: rows rowbase + wr*64 + i*16 + l16, 16B chunk at k-offset quad*8
    const unsigned short* a0 = qn + (size_t)(rowbase + wr*64 + l16) * DDIM + quad * 8;
    const unsigned short* b0 = pn + (size_t)(colbase + wc*64 + l16) * DDIM + quad * 8;

    f32x4 acc[4][4];
    #pragma unroll
    for (int i = 0; i < 4; ++i)
        #pragma unroll
        for (int j = 0; j < 4; ++j) acc[i][j] = (f32x4)0.0f;

    // 2-deep register double buffer. All indices compile-time (full unroll).
    bf16x8 af[2][4], bf[2][4];

#define LOADF(buf, ks) do {                                                  \
        _Pragma("unroll")                                                    \
        for (int i = 0; i < 4; ++i) {                                        \
            af[buf][i] = *(const bf16x8*)(a0 + (size_t)i * 16 * DDIM + (ks) * 32); \
            bf[buf][i] = *(const bf16x8*)(b0 + (size_t)i * 16 * DDIM + (ks) * 32); \
        }                                                                    \
    } while (0)

    LOADF(0, 0);

    #pragma unroll
    for (int ks = 0; ks < 8; ++ks) {
        if (ks < 7) LOADF((ks + 1) & 1, ks + 1);   // prefetch next K-step
        const int cur = ks & 1;
        #pragma unroll
        for (int i = 0; i < 4; ++i)
            #pragma unroll
            for (int j = 0; j < 4; ++j)
                acc[i][j] = __builtin_amdgcn_mfma_f32_16x16x32_bf16(
                    af[cur][i], bf[cur][j], acc[i][j], 0, 0, 0);
    }
#undef LOADF

    // epilogue ------------------------------------------------------------
    #pragma unroll
    for (int i = 0; i < 4; ++i)
        #pragma unroll
        for (int r = 0; r < 4; ++r) {
            float s = __expf(acc[i][0][r] * INV_TEMP)
                    + __expf(acc[i][1][r] * INV_TEMP)
                    + __expf(acc[i][2][r] * INV_TEMP)
                    + __expf(acc[i][3][r] * INV_TEMP);
            s += __shfl_xor(s, 1);
            s += __shfl_xor(s, 2);
            s += __shfl_xor(s, 4);
            s += __shfl_xor(s, 8);
            if (l16 == 0)
                red[wc * 128 + wr * 64 + i * 16 + quad * 4 + r] = s;
        }
    __syncthreads();

    if (tid < 128)
        part[(size_t)blockIdx.x * NROWS + rowbase + tid] = red[tid] + red[128 + tid];
}

// ---------------------------------------------------------------------------
// Kernel 3: per-row total + log - diag, block-partial loss sums.
// ---------------------------------------------------------------------------
__global__ __launch_bounds__(128) void rowsum_kernel(
    const float* __restrict__ part, const float* __restrict__ diag,
    float* __restrict__ loss_part)
{
    const int row = blockIdx.x * 128 + threadIdx.x;
    float s = 0.0f;
    #pragma unroll 4
    for (int cb = 0; cb < 64; ++cb)
        s += part[(size_t)cb * NROWS + row];     // coalesced across threads
    float v = logf(s) - diag[row];

    #pragma unroll
    for (int m = 1; m < 64; m <<= 1) v += __shfl_xor(v, m);
    __shared__ float wsum[2];
    if ((threadIdx.x & 63) == 0) wsum[threadIdx.x >> 6] = v;
    __syncthreads();
    if (threadIdx.x == 0) loss_part[blockIdx.x] = wsum[0] + wsum[1];
}

// ---------------------------------------------------------------------------
// Kernel 4: final mean over 64 block partials. One wave.
// ---------------------------------------------------------------------------
__global__ __launch_bounds__(64) void final_kernel(
    const float* __restrict__ loss_part, float* __restrict__ out)
{
    float v = loss_part[threadIdx.x];
    #pragma unroll
    for (int m = 1; m < 64; m <<= 1) v += __shfl_xor(v, m);
    if (threadIdx.x == 0) out[0] = v * (1.0f / NROWS);
}

// ---------------------------------------------------------------------------
extern "C" void kernel_launch(void* const* d_in, const int* in_sizes, int n_in,
                              void* d_out, int out_size, void* d_ws, size_t ws_size,
                              hipStream_t stream)
{
    const float* q = (const float*)d_in[0];
    const float* p = (const float*)d_in[1];

    char* ws = (char*)d_ws;
    unsigned short* qn   = (unsigned short*)ws;                          // 4 MB
    unsigned short* pn   = (unsigned short*)(ws + (size_t)NROWS*DDIM*2); // 4 MB
    float* part      = (float*)(ws + 2*(size_t)NROWS*DDIM*2);            // 2 MB
    float* diag      = part + 64 * (size_t)NROWS;                        // 32 KB
    float* loss_part = diag + NROWS;                                     // 256 B

    norm_diag_kernel<<<NROWS/4, 256, 0, stream>>>(q, p, qn, pn, diag);

    dim3 grid(64, 64);   // colblocks x rowblocks
    simexp_kernel<<<grid, 256, 0, stream>>>(qn, pn, part);

    rowsum_kernel<<<64, 128, 0, stream>>>(part, diag, loss_part);
    final_kernel<<<1, 64, 0, stream>>>(loss_part, (float*)d_out);
}

// Round 3
// 136.051 us; speedup vs baseline: 1.4641x; 1.4641x over previous
//
#include <hip/hip_runtime.h>
#include <hip/hip_bf16.h>

#define NROWS 8192
#define DDIM  256
#define INV_TEMP 20.0f   // 1/0.05

typedef __attribute__((ext_vector_type(8))) short bf16x8;
typedef __attribute__((ext_vector_type(4))) float f32x4;

// async global->LDS, 16B per lane. LDS dest = uniform base + lane*16.
__device__ static inline void async16(const void* g, void* l) {
    __builtin_amdgcn_global_load_lds(
        (const __attribute__((address_space(1))) void*)g,
        (__attribute__((address_space(3))) void*)l, 16, 0, 0);
}

// ---------------------------------------------------------------------------
// Kernel 1: per-row L2-normalize q and p (fp32), emit bf16 copies, fp32 diag.
// One wave per row, 4 rows (4 waves) per block.
// ---------------------------------------------------------------------------
__global__ __launch_bounds__(256) void norm_diag_kernel(
    const float* __restrict__ q, const float* __restrict__ p,
    unsigned short* __restrict__ qn, unsigned short* __restrict__ pn,
    float* __restrict__ diag)
{
    const int row  = (blockIdx.x << 2) + (threadIdx.x >> 6);
    const int lane = threadIdx.x & 63;

    const float4 qv = ((const float4*)(q + (size_t)row * DDIM))[lane];
    const float4 pv = ((const float4*)(p + (size_t)row * DDIM))[lane];

    float sq = qv.x*qv.x + qv.y*qv.y + qv.z*qv.z + qv.w*qv.w;
    float sp = pv.x*pv.x + pv.y*pv.y + pv.z*pv.z + pv.w*pv.w;
    #pragma unroll
    for (int m = 1; m < 64; m <<= 1) {
        sq += __shfl_xor(sq, m);
        sp += __shfl_xor(sp, m);
    }
    const float qs = 1.0f / fmaxf(sqrtf(sq), 1e-8f);
    const float ps = 1.0f / fmaxf(sqrtf(sp), 1e-8f);

    const float qx = qv.x*qs, qy = qv.y*qs, qz = qv.z*qs, qw = qv.w*qs;
    const float px = pv.x*ps, py = pv.y*ps, pz = pv.z*ps, pw = pv.w*ps;

    float d = qx*px + qy*py + qz*pz + qw*pw;
    #pragma unroll
    for (int m = 1; m < 64; m <<= 1) d += __shfl_xor(d, m);
    if (lane == 0) diag[row] = d * INV_TEMP;

    union { unsigned short u16[4]; uint2 v; } uq, up;
    {
        __hip_bfloat16 b;
        b = __float2bfloat16(qx); uq.u16[0] = *(unsigned short*)&b;
        b = __float2bfloat16(qy); uq.u16[1] = *(unsigned short*)&b;
        b = __float2bfloat16(qz); uq.u16[2] = *(unsigned short*)&b;
        b = __float2bfloat16(qw); uq.u16[3] = *(unsigned short*)&b;
        b = __float2bfloat16(px); up.u16[0] = *(unsigned short*)&b;
        b = __float2bfloat16(py); up.u16[1] = *(unsigned short*)&b;
        b = __float2bfloat16(pz); up.u16[2] = *(unsigned short*)&b;
        b = __float2bfloat16(pw); up.u16[3] = *(unsigned short*)&b;
    }
    *(uint2*)(qn + (size_t)row * DDIM + lane * 4) = uq.v;
    *(uint2*)(pn + (size_t)row * DDIM + lane * 4) = up.v;
}

// ---------------------------------------------------------------------------
// Kernel 2: fused GEMM + sum-exp, depth-2 prefetch pipeline (R1 structure)
// + XCD-chunked block swizzle (T1).
//
// Swizzle rationale: with default dispatch each per-XCD L2 (4 MiB) samples
// ~all 16 MB of panel data -> staging reads are L2 misses paying L3 latency
// (~500-900 cyc) at every vmcnt+barrier. Remap so XCD x (= L&7 under
// round-robin dispatch) owns rowblocks [8x,8x+8) x all colblocks, rows-fast:
// B col-panel (64 KB) reused by 8 consecutive blocks on the same XCD,
// A-slice (512 KB) pinned. Hot set ~1.3 MB < 4 MiB -> staging L2-hits,
// covered by the depth-2 prefetch. nwg=4096 % 8 == 0 -> bijective.
//
// Pipeline: 3 LDS buffers (16 KB each), stage(t) issued at iter t-2, raw
// s_barrier + counted s_waitcnt vmcnt(4) (never drains to 0 in-loop).
// ---------------------------------------------------------------------------
__global__ __launch_bounds__(256, 3) void simexp_kernel(
    const unsigned short* __restrict__ qn,
    const unsigned short* __restrict__ pn,
    float* __restrict__ part)       // [64 colblocks][8192 rows]
{
    __shared__ unsigned char lds[3 * 16384];   // 3 x (As 8KB | Bs 8KB)

    const int tid  = threadIdx.x;
    const int lane = tid & 63;
    const int w    = tid >> 6;        // wave 0..3
    const int wr   = w >> 1;          // wave row (0..1)
    const int wc   = w & 1;           // wave col (0..1)
    const int quad = lane >> 4;
    const int l16  = lane & 15;

    // ---- XCD-chunked swizzle (bijective on 4096 blocks) ----
    const int L   = blockIdx.y * 64 + blockIdx.x;  // linear dispatch id
    const int xcd = L & 7;                          // round-robin XCD
    const int c   = L >> 3;                         // index within XCD chunk
    const int rowblk = xcd * 8 + (c & 7);           // rows-fast within chunk
    const int colblk = c >> 3;
    const int rowbase = rowblk * 128;
    const int colbase = colblk * 128;

    // staging source addresses: wave w stages A row-tiles {2w, 2w+1} and
    // B col-tiles {2w, 2w+1}. lane l -> row (l&15), 16B chunk (l>>4).
    const unsigned short* gA0 = qn + (size_t)(rowbase + (2*w  )*16 + l16) * DDIM + quad * 8;
    const unsigned short* gA1 = qn + (size_t)(rowbase + (2*w+1)*16 + l16) * DDIM + quad * 8;
    const unsigned short* gB0 = pn + (size_t)(colbase + (2*w  )*16 + l16) * DDIM + quad * 8;
    const unsigned short* gB1 = pn + (size_t)(colbase + (2*w+1)*16 + l16) * DDIM + quad * 8;

    f32x4 acc[4][4];
    #pragma unroll
    for (int i = 0; i < 4; ++i)
        #pragma unroll
        for (int j = 0; j < 4; ++j) acc[i][j] = (f32x4)0.0f;

    // 4 global_load_lds per STAGE per wave -> vmcnt granularity of 4.
#define STAGE(buf, ks) do {                                             \
        unsigned char* _b = lds + (buf) * 16384;                        \
        async16(gA0 + (ks) * 32, _b +        (2*w    ) * 1024);         \
        async16(gA1 + (ks) * 32, _b +        (2*w + 1) * 1024);         \
        async16(gB0 + (ks) * 32, _b + 8192 + (2*w    ) * 1024);         \
        async16(gB1 + (ks) * 32, _b + 8192 + (2*w + 1) * 1024);         \
    } while (0)

    STAGE(0, 0);
    STAGE(1, 1);
    asm volatile("s_waitcnt vmcnt(4)" ::: "memory");   // stage(0) landed
    __builtin_amdgcn_s_barrier();
    asm volatile("" ::: "memory");

    #pragma unroll
    for (int ks = 0; ks < 8; ++ks) {
        if (ks < 6) STAGE((ks + 2) % 3, ks + 2);       // issue 2 tiles ahead

        const unsigned char* ba = lds + (ks % 3) * 16384;
        bf16x8 af[4], bf[4];
        #pragma unroll
        for (int i = 0; i < 4; ++i)
            af[i] = *(const bf16x8*)(ba + (wr*4 + i) * 1024 + quad * 256 + l16 * 16);
        #pragma unroll
        for (int j = 0; j < 4; ++j)
            bf[j] = *(const bf16x8*)(ba + 8192 + (wc*4 + j) * 1024 + quad * 256 + l16 * 16);

        #pragma unroll
        for (int i = 0; i < 4; ++i)
            #pragma unroll
            for (int j = 0; j < 4; ++j)
                acc[i][j] = __builtin_amdgcn_mfma_f32_16x16x32_bf16(
                    af[i], bf[j], acc[i][j], 0, 0, 0);

        if (ks < 7) {
            if (ks < 6) { asm volatile("s_waitcnt vmcnt(4)" ::: "memory"); } // stage(ks+1) done
            else        { asm volatile("s_waitcnt vmcnt(0)" ::: "memory"); } // stage(7) done
            __builtin_amdgcn_s_barrier();
            asm volatile("" ::: "memory");
        }
    }
#undef STAGE

    // epilogue ------------------------------------------------------------
    __syncthreads();                   // done with staged tiles; reuse LDS
    float* red = (float*)lds;          // 256 floats: [wc][128 rows]

    #pragma unroll
    for (int i = 0; i < 4; ++i)
        #pragma unroll
        for (int r = 0; r < 4; ++r) {
            float s = __expf(acc[i][0][r] * INV_TEMP)
                    + __expf(acc[i][1][r] * INV_TEMP)
                    + __expf(acc[i][2][r] * INV_TEMP)
                    + __expf(acc[i][3][r] * INV_TEMP);
            s += __shfl_xor(s, 1);
            s += __shfl_xor(s, 2);
            s += __shfl_xor(s, 4);
            s += __shfl_xor(s, 8);
            if (l16 == 0)
                red[wc * 128 + wr * 64 + i * 16 + quad * 4 + r] = s;
        }
    __syncthreads();

    if (tid < 128)
        part[(size_t)colblk * NROWS + rowbase + tid] = red[tid] + red[128 + tid];
}

// ---------------------------------------------------------------------------
// Kernel 3: per-row total + log - diag, block-partial loss sums.
// ---------------------------------------------------------------------------
__global__ __launch_bounds__(128) void rowsum_kernel(
    const float* __restrict__ part, const float* __restrict__ diag,
    float* __restrict__ loss_part)
{
    const int row = blockIdx.x * 128 + threadIdx.x;
    float s = 0.0f;
    #pragma unroll 4
    for (int cb = 0; cb < 64; ++cb)
        s += part[(size_t)cb * NROWS + row];     // coalesced across threads
    float v = logf(s) - diag[row];

    #pragma unroll
    for (int m = 1; m < 64; m <<= 1) v += __shfl_xor(v, m);
    __shared__ float wsum[2];
    if ((threadIdx.x & 63) == 0) wsum[threadIdx.x >> 6] = v;
    __syncthreads();
    if (threadIdx.x == 0) loss_part[blockIdx.x] = wsum[0] + wsum[1];
}

// ---------------------------------------------------------------------------
// Kernel 4: final mean over 64 block partials. One wave.
// ---------------------------------------------------------------------------
__global__ __launch_bounds__(64) void final_kernel(
    const float* __restrict__ loss_part, float* __restrict__ out)
{
    float v = loss_part[threadIdx.x];
    #pragma unroll
    for (int m = 1; m < 64; m <<= 1) v += __shfl_xor(v, m);
    if (threadIdx.x == 0) out[0] = v * (1.0f / NROWS);
}

// ---------------------------------------------------------------------------
extern "C" void kernel_launch(void* const* d_in, const int* in_sizes, int n_in,
                              void* d_out, int out_size, void* d_ws, size_t ws_size,
                              hipStream_t stream)
{
    const float* q = (const float*)d_in[0];
    const float* p = (const float*)d_in[1];

    char* ws = (char*)d_ws;
    unsigned short* qn   = (unsigned short*)ws;                          // 4 MB
    unsigned short* pn   = (unsigned short*)(ws + (size_t)NROWS*DDIM*2); // 4 MB
    float* part      = (float*)(ws + 2*(size_t)NROWS*DDIM*2);            // 2 MB
    float* diag      = part + 64 * (size_t)NROWS;                        // 32 KB
    float* loss_part = diag + NROWS;                                     // 256 B

    norm_diag_kernel<<<NROWS/4, 256, 0, stream>>>(q, p, qn, pn, diag);

    dim3 grid(64, 64);   // colblocks x rowblocks (remapped in-kernel)
    simexp_kernel<<<grid, 256, 0, stream>>>(qn, pn, part);

    rowsum_kernel<<<64, 128, 0, stream>>>(part, diag, loss_part);
    final_kernel<<<1, 64, 0, stream>>>(loss_part, (float*)d_out);
}